// Round 1
// baseline (18614.832 us; speedup 1.0000x reference)
//
#include <hip/hip_runtime.h>
#include <cstdint>

#define N_NODES 10000
#define N_EDGES 500000
#define E_TOT   510000      // + self loops
#define IN_DIM  512
#define HID     256
#define VOCAB   1000

typedef _Float16 h2v __attribute__((ext_vector_type(2)));

__device__ __forceinline__ float fdot2f(h2v a, h2v b, float c) {
#if __has_builtin(__builtin_amdgcn_fdot2)
    return __builtin_amdgcn_fdot2(a, b, c, false);
#else
    return c + (float)a[0] * (float)b[0] + (float)a[1] * (float)b[1];
#endif
}

__device__ __forceinline__ float sigmoidf_(float x) {
    return 1.f / (1.f + __expf(-x));
}
__device__ __forceinline__ float tanhf_(float x) {
    float ax = fabsf(x);
    float e  = __expf(-2.f * ax);
    float r  = (1.f - e) / (1.f + e);
    return x < 0.f ? -r : r;
}

// ---------------------------------------------------------------------------
// fp32 tiled GEMM: C[M,N] = A[M,K] @ (TRANSB ? B[N,K]^T : B[K,N]) (+bias +bias2)
// EPI==1: permuted store for LSTM pre-activations: col n -> (n&255)*4 + (n>>8)
// so the LSTM can read gates {i,f,g,o} of element r as one float4.
// ---------------------------------------------------------------------------
template<bool TRANSB, int EPI>
__global__ __launch_bounds__(256) void gemm64(
    const float* __restrict__ A, const float* __restrict__ B,
    const float* __restrict__ bias, const float* __restrict__ bias2,
    float* __restrict__ C, int M, int N, int K, int ldc)
{
    __shared__ float As[16][68];
    __shared__ float Bs[16][68];
    const int tid = threadIdx.x;
    const int tx = tid & 15, ty = tid >> 4;
    const int m0 = blockIdx.x * 64, n0 = blockIdx.y * 64;
    float acc[4][4] = {};

    for (int k0 = 0; k0 < K; k0 += 16) {
        {   // A tile 64x16 (K is always a multiple of 16)
            int row = tid >> 2, col = (tid & 3) << 2;
            float4 v = make_float4(0.f, 0.f, 0.f, 0.f);
            if (m0 + row < M)
                v = *(const float4*)(A + (size_t)(m0 + row) * K + k0 + col);
            As[col + 0][row] = v.x; As[col + 1][row] = v.y;
            As[col + 2][row] = v.z; As[col + 3][row] = v.w;
        }
        if (!TRANSB) {  // B tile 16x64 from [K,N]
            int row = tid >> 4, col = (tid & 15) << 2;
            const float* bp = B + (size_t)(k0 + row) * N + n0 + col;
            float4 v = make_float4(0.f, 0.f, 0.f, 0.f);
            if (n0 + col + 3 < N) v = *(const float4*)bp;
            else {
                if (n0 + col + 0 < N) v.x = bp[0];
                if (n0 + col + 1 < N) v.y = bp[1];
                if (n0 + col + 2 < N) v.z = bp[2];
            }
            *(float4*)&Bs[row][col] = v;
        } else {        // B tile from [N,K] (transposed access)
            int nr = tid >> 2, kc = (tid & 3) << 2;
            float4 v = make_float4(0.f, 0.f, 0.f, 0.f);
            if (n0 + nr < N)
                v = *(const float4*)(B + (size_t)(n0 + nr) * K + k0 + kc);
            Bs[kc + 0][nr] = v.x; Bs[kc + 1][nr] = v.y;
            Bs[kc + 2][nr] = v.z; Bs[kc + 3][nr] = v.w;
        }
        __syncthreads();
        #pragma unroll
        for (int kk = 0; kk < 16; ++kk) {
            float a[4], b[4];
            *(float4*)a = *(const float4*)&As[kk][ty << 2];
            *(float4*)b = *(const float4*)&Bs[kk][tx << 2];
            #pragma unroll
            for (int i = 0; i < 4; ++i)
                #pragma unroll
                for (int j = 0; j < 4; ++j)
                    acc[i][j] = fmaf(a[i], b[j], acc[i][j]);
        }
        __syncthreads();
    }
    #pragma unroll
    for (int i = 0; i < 4; ++i) {
        int m = m0 + (ty << 2) + i;
        if (m >= M) continue;
        #pragma unroll
        for (int j = 0; j < 4; ++j) {
            int n = n0 + (tx << 2) + j;
            if (n >= N) continue;
            float v = acc[i][j];
            if (bias)  v += bias[n];
            if (bias2) v += bias2[n];
            if (EPI == 1)
                C[(size_t)m * ldc + (((n & 255) << 2) + (n >> 8))] = v;
            else
                C[(size_t)m * ldc + n] = v;
        }
    }
}

// ---------------------------------------------------------------------------
// per-node attention scores: s_src[n] = h[n,:].a_src ; s_dst[n] = h[n,:].a_dst
// one wave per node, lane handles 4 channels
// ---------------------------------------------------------------------------
__global__ __launch_bounds__(256) void scores_kernel(
    const float* __restrict__ H, const float* __restrict__ asrc,
    const float* __restrict__ adst, float* __restrict__ ssrc,
    float* __restrict__ sdst)
{
    int node = blockIdx.x * 4 + (threadIdx.x >> 6);
    int lane = threadIdx.x & 63;
    if (node >= N_NODES) return;
    float4 h = ((const float4*)H)[node * 64 + lane];
    float4 a = ((const float4*)asrc)[lane];
    float4 b = ((const float4*)adst)[lane];
    float ps = h.x * a.x + h.y * a.y + h.z * a.z + h.w * a.w;
    float pd = h.x * b.x + h.y * b.y + h.z * b.z + h.w * b.w;
    #pragma unroll
    for (int off = 32; off > 0; off >>= 1) {
        ps += __shfl_xor(ps, off);
        pd += __shfl_xor(pd, off);
    }
    if (lane == 0) { ssrc[node] = ps; sdst[node] = pd; }
}

// ---------------------------------------------------------------------------
// edge weights w_e = exp(leaky_relu(s_src[src]+s_dst[dst])) and denominator.
// Max-subtraction skipped: |logit| <= ~6 so exp is safe; alpha is identical
// up to rounding. Edges e>=N_EDGES are the appended self-loops.
// ---------------------------------------------------------------------------
__global__ __launch_bounds__(256) void edge_w_kernel(
    const int* __restrict__ ei, const float* __restrict__ ssrc,
    const float* __restrict__ sdst, float* __restrict__ wbuf,
    float* __restrict__ denom)
{
    int e = blockIdx.x * 256 + threadIdx.x;
    if (e >= E_TOT) return;
    int s, d;
    if (e < N_EDGES) { s = ei[e]; d = ei[N_EDGES + e]; }
    else             { s = d = e - N_EDGES; }
    float v = ssrc[s] + sdst[d];
    v = (v > 0.f) ? v : 0.2f * v;
    float w = __expf(v);
    wbuf[e] = w;
    unsafeAtomicAdd(&denom[d], w);
}

// one wave per edge: lane covers 4 channels; hw fp32 atomics into scatter buf
__global__ __launch_bounds__(256) void scatter_kernel(
    const int* __restrict__ ei, const float* __restrict__ H,
    const float* __restrict__ wbuf, float* __restrict__ S)
{
    int e = blockIdx.x * 4 + (threadIdx.x >> 6);
    int lane = threadIdx.x & 63;
    if (e >= E_TOT) return;
    int s, d;
    if (e < N_EDGES) { s = ei[e]; d = ei[N_EDGES + e]; }
    else             { s = d = e - N_EDGES; }
    float w = wbuf[e];
    float4 h = ((const float4*)H)[s * 64 + lane];
    float* outp = S + (size_t)d * HID + lane * 4;
    unsafeAtomicAdd(outp + 0, w * h.x);
    unsafeAtomicAdd(outp + 1, w * h.y);
    unsafeAtomicAdd(outp + 2, w * h.z);
    unsafeAtomicAdd(outp + 3, w * h.w);
}

// out[n,c] = act(scatter[n,c]/denom[n] + b[c])
__global__ __launch_bounds__(256) void finalize_kernel(
    const float* __restrict__ S, const float* __restrict__ denom,
    const float* __restrict__ bias, float* __restrict__ H, int relu)
{
    int idx = blockIdx.x * 256 + threadIdx.x;
    int n = idx >> 8, ci = idx & 255;
    float v = S[idx] / denom[n] + bias[ci];
    if (relu) v = fmaxf(v, 0.f);
    H[idx] = v;
}

// ---------------------------------------------------------------------------
// LSTM scan: single workgroup (one CU), 512 threads = 8 waves.
// thread t: element r0 = t&255, column half s = t>>8 (cols [128s,128s+128)).
// Gate rows {r0, r0+256, r0+512} as f16 pairs in VGPRs (192 dwords),
// row r0+768 (o gate) in XOR-swizzled LDS (128 KB).  fp32 accumulate via
// v_dot2_f32_f16. pre-activations prefetched one step ahead (global float4,
// gate-interleaved layout from gemm64<...,EPI=1>).
// ---------------------------------------------------------------------------
__global__ __launch_bounds__(512, 2) void lstm_kernel(
    const float* __restrict__ Whh,   // [1024][256] fp32
    const float* __restrict__ pre4,  // [T][256][4]  (i,f,g,o per element)
    float* __restrict__ hs,          // [T][256]
    int T)
{
    __shared__ uint4  oW4[512 * 16]; // 128 KB o-gate weights, 16B-unit swizzle
    __shared__ uint4  h4[32];        // 256 x f16 hidden state (packed pairs)
    __shared__ float4 pf4[512];      // partial gate sums

    const int t  = threadIdx.x;
    const int r0 = t & 255, s = t >> 8;
    const int sw = t & 7;

    h2v wi[64], wf[64], wg[64];
    {
        const float2* Wr = (const float2*)(Whh + (size_t)r0 * 256 + s * 128);
        #pragma unroll
        for (int j = 0; j < 64; ++j) {
            float2 v = Wr[j]; h2v w; w[0] = (_Float16)v.x; w[1] = (_Float16)v.y; wi[j] = w;
        }
        Wr = (const float2*)(Whh + (size_t)(r0 + 256) * 256 + s * 128);
        #pragma unroll
        for (int j = 0; j < 64; ++j) {
            float2 v = Wr[j]; h2v w; w[0] = (_Float16)v.x; w[1] = (_Float16)v.y; wf[j] = w;
        }
        Wr = (const float2*)(Whh + (size_t)(r0 + 512) * 256 + s * 128);
        #pragma unroll
        for (int j = 0; j < 64; ++j) {
            float2 v = Wr[j]; h2v w; w[0] = (_Float16)v.x; w[1] = (_Float16)v.y; wg[j] = w;
        }
        const float2* Wo = (const float2*)(Whh + (size_t)(r0 + 768) * 256 + s * 128);
        #pragma unroll
        for (int u = 0; u < 16; ++u) {
            unsigned int dd[4];
            #pragma unroll
            for (int q = 0; q < 4; ++q) {
                float2 v = Wo[u * 4 + q];
                h2v w; w[0] = (_Float16)v.x; w[1] = (_Float16)v.y;
                dd[q] = __builtin_bit_cast(unsigned int, w);
            }
            oW4[t * 16 + (u ^ sw)] = make_uint4(dd[0], dd[1], dd[2], dd[3]);
        }
    }
    if (t < 32) h4[t] = make_uint4(0, 0, 0, 0);   // h_0 = 0
    float c = 0.f;                                 // c_0 = 0 (threads < 256)
    float4 pren = make_float4(0.f, 0.f, 0.f, 0.f);
    if (t < 256) pren = ((const float4*)pre4)[t];
    __syncthreads();

    for (int step = 0; step < T; ++step) {
        float4 pnxt = pren;
        if (t < 256) {  // prefetch next step's pre-activations under the dots
            int ni = (step + 1 < T) ? (step + 1) : step;
            pnxt = ((const float4*)pre4)[(size_t)ni * 256 + t];
        }
        float ai = 0.f, af = 0.f, ag = 0.f, ao = 0.f;
        #pragma unroll
        for (int ch = 0; ch < 8; ++ch) {
            uint4 ha = h4[s * 16 + ch * 2 + 0];                 // broadcast
            uint4 hb = h4[s * 16 + ch * 2 + 1];
            uint4 oa = oW4[t * 16 + ((ch * 2 + 0) ^ sw)];       // swizzled
            uint4 ob = oW4[t * 16 + ((ch * 2 + 1) ^ sw)];
            unsigned int hu[8] = {ha.x, ha.y, ha.z, ha.w, hb.x, hb.y, hb.z, hb.w};
            unsigned int ou[8] = {oa.x, oa.y, oa.z, oa.w, ob.x, ob.y, ob.z, ob.w};
            #pragma unroll
            for (int j = 0; j < 8; ++j) {
                h2v hh = __builtin_bit_cast(h2v, hu[j]);
                h2v oo = __builtin_bit_cast(h2v, ou[j]);
                ai = fdot2f(wi[ch * 8 + j], hh, ai);
                af = fdot2f(wf[ch * 8 + j], hh, af);
                ag = fdot2f(wg[ch * 8 + j], hh, ag);
                ao = fdot2f(oo,             hh, ao);
            }
        }
        pf4[t] = make_float4(ai, af, ag, ao);
        __syncthreads();
        if (t < 256) {
            float4 p0 = pf4[t], p1 = pf4[t + 256];
            float gi = p0.x + p1.x + pren.x;
            float gf = p0.y + p1.y + pren.y;
            float gg = p0.z + p1.z + pren.z;
            float go = p0.w + p1.w + pren.w;
            float i_ = sigmoidf_(gi);
            float f_ = sigmoidf_(gf);
            float g_ = tanhf_(gg);
            float o_ = sigmoidf_(go);
            c = fmaf(f_, c, i_ * g_);
            float hv = o_ * tanhf_(c);
            hs[(size_t)step * HID + t] = hv;
            ((_Float16*)h4)[t] = (_Float16)hv;   // publish h_{t} for next step
            pren = pnxt;
        }
        __syncthreads();
    }
}

// ---------------------------------------------------------------------------
extern "C" void kernel_launch(void* const* d_in, const int* in_sizes, int n_in,
                              void* d_out, int out_size, void* d_ws, size_t ws_size,
                              hipStream_t stream)
{
    const float* x   = (const float*)d_in[0];
    const float* W1  = (const float*)d_in[1];
    const float* as1 = (const float*)d_in[2];
    const float* ad1 = (const float*)d_in[3];
    const float* b1  = (const float*)d_in[4];
    const float* W2  = (const float*)d_in[5];
    const float* as2 = (const float*)d_in[6];
    const float* ad2 = (const float*)d_in[7];
    const float* b2  = (const float*)d_in[8];
    const float* Wih = (const float*)d_in[9];
    const float* Whh = (const float*)d_in[10];
    const float* bih = (const float*)d_in[11];
    const float* bhh = (const float*)d_in[12];
    const float* Wfc = (const float*)d_in[13];
    const float* bfc = (const float*)d_in[14];
    const int*   ei  = (const int*)d_in[15];
    float* out = (float*)d_out;

    // workspace layout (floats); total ~74 MB
    float* ws    = (float*)d_ws;
    float* A     = ws;             // [10000,256] h_lin, later hs
    float* Bsc   = ws +  2560000;  // [10000,256] scatter accumulator
    float* Cbuf  = ws +  5120000;  // [10000,256] activated GAT output
    float* pre   = ws +  7680000;  // [10000,1024] LSTM input proj (permuted)
    float* wbuf  = ws + 17920000;  // [510000] edge weights
    float* denom = ws + 18430000;  // [10000]
    float* ssrc  = ws + 18440000;  // [10000]
    float* sdst  = ws + 18450000;  // [10000]

    dim3 blk(256);

    // ---- GAT layer 1 ----
    gemm64<false, 0><<<dim3(157, 4), blk, 0, stream>>>(
        x, W1, nullptr, nullptr, A, N_NODES, HID, IN_DIM, HID);
    scores_kernel<<<2500, blk, 0, stream>>>(A, as1, ad1, ssrc, sdst);
    hipMemsetAsync(Bsc, 0, (size_t)N_NODES * HID * 4, stream);
    hipMemsetAsync(denom, 0, (size_t)N_NODES * 4, stream);
    edge_w_kernel<<<(E_TOT + 255) / 256, blk, 0, stream>>>(ei, ssrc, sdst, wbuf, denom);
    scatter_kernel<<<E_TOT / 4, blk, 0, stream>>>(ei, A, wbuf, Bsc);
    finalize_kernel<<<N_NODES, blk, 0, stream>>>(Bsc, denom, b1, Cbuf, 1);

    // ---- GAT layer 2 ----
    gemm64<false, 0><<<dim3(157, 4), blk, 0, stream>>>(
        Cbuf, W2, nullptr, nullptr, A, N_NODES, HID, HID, HID);
    scores_kernel<<<2500, blk, 0, stream>>>(A, as2, ad2, ssrc, sdst);
    hipMemsetAsync(Bsc, 0, (size_t)N_NODES * HID * 4, stream);
    hipMemsetAsync(denom, 0, (size_t)N_NODES * 4, stream);
    edge_w_kernel<<<(E_TOT + 255) / 256, blk, 0, stream>>>(ei, ssrc, sdst, wbuf, denom);
    scatter_kernel<<<E_TOT / 4, blk, 0, stream>>>(ei, A, wbuf, Bsc);
    finalize_kernel<<<N_NODES, blk, 0, stream>>>(Bsc, denom, b2, Cbuf, 0);

    // ---- LSTM ----
    gemm64<true, 1><<<dim3(157, 16), blk, 0, stream>>>(
        Cbuf, Wih, bih, bhh, pre, N_NODES, 4 * HID, HID, 4 * HID);
    lstm_kernel<<<1, 512, 0, stream>>>(Whh, pre, A, N_NODES);

    // ---- FC ----
    gemm64<true, 0><<<dim3(157, 16), blk, 0, stream>>>(
        A, Wfc, bfc, nullptr, out, N_NODES, VOCAB, HID, VOCAB);
}